// Round 9
// baseline (397.746 us; speedup 1.0000x reference)
//
#include <hip/hip_runtime.h>
#include <hip/hip_bf16.h>
#include <math.h>

#define B_ 4
#define S_ 2048
#define H_ 1024
#define KC 128
#define EPSF 1e-8f
#define NB 512   // persistent grid: 2 blocks/CU on 256 CUs

typedef __attribute__((ext_vector_type(8))) short bf16x8;
typedef __attribute__((ext_vector_type(4))) float f32x4;

static __device__ inline unsigned short f2b(float f) {
    unsigned u = __float_as_uint(f);
    return (unsigned short)((u + 0x7fffu + ((u >> 16) & 1u)) >> 16);  // RNE
}

static __device__ inline unsigned long long shflx64(unsigned long long v, int m) {
    int lo = __shfl_xor((int)(unsigned)(v & 0xffffffffull), m, 64);
    int hi = __shfl_xor((int)(unsigned)(v >> 32), m, 64);
    return ((unsigned long long)(unsigned)hi << 32) | (unsigned)lo;
}

#define CROSS_STAGE(k, j) do {                                              \
    const int lm = (j) >> 3;                                                \
    const bool upL  = (((lane) * 8) & (k)) == 0;                            \
    const bool lowr = ((lane) & lm) == 0;                                   \
    _Pragma("unroll")                                                       \
    for (int r = 0; r < 8; ++r) {                                           \
        unsigned long long o = shflx64(e[r], lm);                           \
        e[r] = ((upL == lowr) == (e[r] < o)) ? e[r] : o;                    \
    }                                                                       \
} while (0)

#define INTRA_STAGE(j, k) do {                                              \
    _Pragma("unroll")                                                       \
    for (int r = 0; r < 8; ++r) if (!(r & (j))) {                           \
        bool up = ((((lane) * 8 + r) & (k)) == 0);                          \
        unsigned long long a = e[r], b = e[r | (j)];                        \
        if (up ? (a > b) : (a < b)) { e[r] = b; e[r | (j)] = a; }           \
    }                                                                       \
} while (0)

static __device__ inline void wave_sort512(unsigned long long e[8], int lane) {
    INTRA_STAGE(1, 2);
    INTRA_STAGE(2, 4);  INTRA_STAGE(1, 4);
    INTRA_STAGE(4, 8);  INTRA_STAGE(2, 8);  INTRA_STAGE(1, 8);
    CROSS_STAGE(16, 8);
    INTRA_STAGE(4, 16); INTRA_STAGE(2, 16); INTRA_STAGE(1, 16);
    CROSS_STAGE(32, 16); CROSS_STAGE(32, 8);
    INTRA_STAGE(4, 32); INTRA_STAGE(2, 32); INTRA_STAGE(1, 32);
    CROSS_STAGE(64, 32); CROSS_STAGE(64, 16); CROSS_STAGE(64, 8);
    INTRA_STAGE(4, 64); INTRA_STAGE(2, 64); INTRA_STAGE(1, 64);
    CROSS_STAGE(128, 64); CROSS_STAGE(128, 32); CROSS_STAGE(128, 16);
    CROSS_STAGE(128, 8);
    INTRA_STAGE(4, 128); INTRA_STAGE(2, 128); INTRA_STAGE(1, 128);
    CROSS_STAGE(256, 128); CROSS_STAGE(256, 64); CROSS_STAGE(256, 32);
    CROSS_STAGE(256, 16); CROSS_STAGE(256, 8);
    INTRA_STAGE(4, 256); INTRA_STAGE(2, 256); INTRA_STAGE(1, 256);
    CROSS_STAGE(512, 256); CROSS_STAGE(512, 128); CROSS_STAGE(512, 64);
    CROSS_STAGE(512, 32); CROSS_STAGE(512, 16); CROSS_STAGE(512, 8);
    INTRA_STAGE(4, 512); INTRA_STAGE(2, 512); INTRA_STAGE(1, 512);
}

// Device-scope grid barrier: monotonic counter (no reset inside kernel).
static __device__ inline void grid_sync(unsigned* cnt, unsigned target) {
    __syncthreads();
    if (threadIdx.x == 0) {
        __threadfence();   // release our writes device-wide
        __hip_atomic_fetch_add(cnt, 1u, __ATOMIC_ACQ_REL, __HIP_MEMORY_SCOPE_AGENT);
        while (__hip_atomic_load(cnt, __ATOMIC_ACQUIRE, __HIP_MEMORY_SCOPE_AGENT) < target)
            __builtin_amdgcn_s_sleep(1);
        __threadfence();   // acquire others' writes
    }
    __syncthreads();
}

// ------------------------------------------------------------------
// Single persistent kernel: all six phases with device grid barriers.
// ------------------------------------------------------------------
__global__ __launch_bounds__(256, 2) void fused_all_kernel(
    const float* __restrict__ seq, const float* __restrict__ logits,
    const int* __restrict__ mask, const float* __restrict__ bboxes,
    const float* __restrict__ Wk, const float* __restrict__ bk,
    const float* __restrict__ Wv, const float* __restrict__ bv,
    const float* __restrict__ Wbil, const float* __restrict__ bbil,
    const float* __restrict__ Ws1, const float* __restrict__ bs1,
    const float* __restrict__ Ws2, const float* __restrict__ bs2,
    const float* __restrict__ Wf1, const float* __restrict__ bf1,
    const float* __restrict__ Wf2, const float* __restrict__ bf2,
    unsigned short* __restrict__ Wt,    // [3][1024][1024] bf16 (N-major)
    unsigned short* __restrict__ Abf,   // [1024][1024] bf16; later kbt alias
    unsigned short* __restrict__ reps,  // [1024][1024] bf16 (krep|vrep)
    int* __restrict__ key_idx, int* __restrict__ val_idx,
    unsigned* __restrict__ cnt,
    float* __restrict__ out)            // scores[65536] | kidx[512] | vidx[512]
{
    __shared__ float tile[32][33];
    __shared__ unsigned long long cand[512];
    __shared__ float4 sWs1T[128];
    __shared__ float  sbs1[64];
    __shared__ float4 sWs2v[512];
    __shared__ float4 sbs2v[8];
    __shared__ float  sWf1c0[16];
    __shared__ float4 sWf1v[128];
    __shared__ float  sbf1[16];
    __shared__ float  sWf2[16];

    const int tid  = threadIdx.x;
    const int bid  = blockIdx.x;
    const int lane = tid & 63;
    const int wv   = tid >> 6;
    const int wgid = bid * 4 + wv;          // 0..2047

    // ---- stage spatial-MLP weights in LDS (consumed in phase 5) ----
    for (int i = tid; i < 128; i += 256) {
        int j = i >> 1, q = i & 1;
        sWs1T[i] = (float4){Ws1[(4*q+0)*64+j], Ws1[(4*q+1)*64+j],
                            Ws1[(4*q+2)*64+j], Ws1[(4*q+3)*64+j]};
    }
    for (int i = tid; i < 64;  i += 256) sbs1[i] = bs1[i];
    for (int i = tid; i < 512; i += 256) sWs2v[i] = ((const float4*)Ws2)[i];
    if (tid < 8)  sbs2v[tid] = ((const float4*)bs2)[tid];
    if (tid < 16) sWf1c0[tid] = Wf1[tid];
    for (int i = tid; i < 128; i += 256) {
        int t = i >> 3, q = i & 7;
        sWf1v[i] = (float4){Wf1[(1+4*q+0)*16+t], Wf1[(1+4*q+1)*16+t],
                            Wf1[(1+4*q+2)*16+t], Wf1[(1+4*q+3)*16+t]};
    }
    if (tid < 16) sbf1[tid] = bf1[tid];
    if (tid < 16) sWf2[tid] = Wf2[tid];

    // ================= phase 0: topk (blocks 0..7) | W transpose =========
    if (bid < 8) {
        const int b   = bid >> 1;
        const int cls = (bid & 1) ? 2 : 1;
        unsigned long long e[8];
        #pragma unroll
        for (int r = 0; r < 8; ++r) {
            int s = wv * 512 + lane * 8 + r;
            float l0 = logits[(b * S_ + s) * 3 + 0];
            float l1 = logits[(b * S_ + s) * 3 + 1];
            float l2 = logits[(b * S_ + s) * 3 + 2];
            int pred = 0; float bl = l0;
            if (l1 > bl) { bl = l1; pred = 1; }
            if (l2 > bl) { bl = l2; pred = 2; }
            float c = -1.0f;
            if (pred == cls && mask[b * S_ + s] == 1) {
                double m = (double)bl;
                double e0 = exp((double)l0 - m);
                double e1 = exp((double)l1 - m);
                double e2 = exp((double)l2 - m);
                c = (float)(((cls == 1) ? e1 : e2) / (e0 + e1 + e2));
            }
            unsigned int u = __float_as_uint(c);
            unsigned int mono = (u & 0x80000000u) ? ~u : (u | 0x80000000u);
            e[r] = ((unsigned long long)(~mono) << 32) | (unsigned int)s;
        }
        wave_sort512(e, lane);
        if (lane < 16) {
            #pragma unroll
            for (int r = 0; r < 8; ++r) cand[wv * 128 + lane * 8 + r] = e[r];
        }
        __syncthreads();
        if (wv == 0) {
            #pragma unroll
            for (int r = 0; r < 8; ++r) e[r] = cand[lane * 8 + r];
            wave_sort512(e, lane);
            if (lane < 16) {
                int* idx_out = (bid & 1) ? (val_idx + b * KC) : (key_idx + b * KC);
                float* oidx  = out + B_ * KC * KC + ((bid & 1) ? B_ * KC : 0) + b * KC;
                #pragma unroll
                for (int r = 0; r < 8; ++r) {
                    int sel = (int)(e[r] & 0xffffffffu);
                    idx_out[lane * 8 + r] = sel;
                    oidx[lane * 8 + r] = (float)sel;
                }
            }
        }
    } else {
        for (int t = bid - 8; t < 3072; t += (NB - 8)) {
            const int z = t >> 10;
            const int remb = t & 1023;
            const float* Win = (z == 0) ? Wk : (z == 1) ? Wv : Wbil;
            unsigned short* o = Wt + (size_t)z * H_ * H_;
            const int n0 = (remb & 31) * 32, k0t = (remb >> 5) * 32;
            const int rr = tid >> 3, cc = (tid & 7) * 4;
            float4 v = *(const float4*)(Win + (size_t)(k0t + rr) * H_ + n0 + cc);
            tile[rr][cc + 0] = v.x; tile[rr][cc + 1] = v.y;
            tile[rr][cc + 2] = v.z; tile[rr][cc + 3] = v.w;
            __syncthreads();
            short4 os;
            os.x = (short)f2b(tile[cc + 0][rr]);
            os.y = (short)f2b(tile[cc + 1][rr]);
            os.z = (short)f2b(tile[cc + 2][rr]);
            os.w = (short)f2b(tile[cc + 3][rr]);
            *(short4*)(o + (size_t)(n0 + rr) * H_ + k0t + cc) = os;
            __syncthreads();
        }
    }
    grid_sync(cnt, 1 * NB);

    // ================= phase 1: gather + bf16 convert ====================
    {
        int row = bid * 2 + (tid >> 7);
        int c8  = (tid & 127) * 8;
        int b, srow;
        if (row < 512) { b = row >> 7; srow = key_idx[row]; }
        else           { b = (row - 512) >> 7; srow = val_idx[row - 512]; }
        const float* src = seq + ((size_t)b * S_ + srow) * H_ + c8;
        float4 v1 = *(const float4*)src;
        float4 v2 = *(const float4*)(src + 4);
        short4 oa, ob;
        oa.x = (short)f2b(v1.x); oa.y = (short)f2b(v1.y);
        oa.z = (short)f2b(v1.z); oa.w = (short)f2b(v1.w);
        ob.x = (short)f2b(v2.x); ob.y = (short)f2b(v2.y);
        ob.z = (short)f2b(v2.z); ob.w = (short)f2b(v2.w);
        *(short4*)(Abf + (size_t)row * H_ + c8)     = oa;
        *(short4*)(Abf + (size_t)row * H_ + c8 + 4) = ob;
    }
    grid_sync(cnt, 2 * NB);

    // ================= phase 2: krep/vrep GEMM (16x32 per wave) ==========
    {
        const int m0 = (wgid >> 5) * 16;          // 0..1008
        const int n0 = (wgid & 31) * 32;
        const bool isv = (m0 >= 512);
        const unsigned short* Wm = Wt + (isv ? (size_t)H_ * H_ : 0);
        const float* bias = isv ? bv : bk;
        const int r = lane & 15, kb = (lane >> 4) * 8;
        f32x4 acc0 = {}, acc1 = {};
        const unsigned short* a0 = Abf + (size_t)(m0 + r) * H_ + kb;
        const unsigned short* w0 = Wm + (size_t)(n0 + r) * H_ + kb;
        const unsigned short* w1 = w0 + 16 * H_;
        #pragma unroll 4
        for (int k0 = 0; k0 < H_; k0 += 32) {
            bf16x8 a = *(const bf16x8*)(a0 + k0);
            acc0 = __builtin_amdgcn_mfma_f32_16x16x32_bf16(
                a, *(const bf16x8*)(w0 + k0), acc0, 0, 0, 0);
            acc1 = __builtin_amdgcn_mfma_f32_16x16x32_bf16(
                a, *(const bf16x8*)(w1 + k0), acc1, 0, 0, 0);
        }
        const int orow = (lane >> 4) * 4, ocol = lane & 15;
        #pragma unroll
        for (int g = 0; g < 4; ++g) {
            int m = m0 + orow + g;
            reps[(size_t)m * H_ + n0 + ocol]      = f2b(acc0[g] + bias[n0 + ocol]);
            reps[(size_t)m * H_ + n0 + 16 + ocol] = f2b(acc1[g] + bias[n0 + 16 + ocol]);
        }
    }
    grid_sync(cnt, 3 * NB);

    // ================= phase 3: kbt = krep @ WtBil (16x16 per wave) ======
    {
        const int m0 = (wgid >> 6) * 16;          // 0..496
        const int n0 = (wgid & 63) * 16;
        const int r = lane & 15, kb = (lane >> 4) * 8;
        f32x4 acc = {};
        const unsigned short* a0 = reps + (size_t)(m0 + r) * H_ + kb;
        const unsigned short* w0 = Wt + (size_t)2 * H_ * H_ + (size_t)(n0 + r) * H_ + kb;
        #pragma unroll 4
        for (int k0 = 0; k0 < H_; k0 += 32) {
            acc = __builtin_amdgcn_mfma_f32_16x16x32_bf16(
                *(const bf16x8*)(a0 + k0), *(const bf16x8*)(w0 + k0), acc, 0, 0, 0);
        }
        const int orow = (lane >> 4) * 4, ocol = lane & 15;
        #pragma unroll
        for (int g = 0; g < 4; ++g)
            Abf[(size_t)(m0 + orow + g) * H_ + n0 + ocol] = f2b(acc[g]);  // kbt
    }
    grid_sync(cnt, 4 * NB);

    // ================= phase 4: biaffine (16x16 per wave, 256 waves) =====
    if (wgid < 256) {
        const int b = wgid >> 6, t = wgid & 63;
        const int m0 = (t >> 3) * 16, n0 = (t & 7) * 16;
        const int r = lane & 15, kb = (lane >> 4) * 8;
        f32x4 acc = {};
        const unsigned short* a0 = Abf + ((size_t)b * KC + m0 + r) * H_ + kb;
        const unsigned short* w0 = reps + (size_t)512 * H_
                                 + ((size_t)b * KC + n0 + r) * H_ + kb;
        #pragma unroll 4
        for (int k0 = 0; k0 < H_; k0 += 32) {
            acc = __builtin_amdgcn_mfma_f32_16x16x32_bf16(
                *(const bf16x8*)(a0 + k0), *(const bf16x8*)(w0 + k0), acc, 0, 0, 0);
        }
        float bb = *bbil;
        const int orow = (lane >> 4) * 4, ocol = lane & 15;
        #pragma unroll
        for (int g = 0; g < 4; ++g)
            out[((size_t)b * KC + m0 + orow + g) * KC + n0 + ocol] = acc[g] + bb;
    }
    grid_sync(cnt, 5 * NB);

    // ================= phase 5: spatial features + MLPs ==================
    if (tid < 128) {
        const int b = bid >> 7;          // bid = (b,k) row
        const int k = bid & 127;
        const int v = tid;
        const int gid = bid * 128 + v;

        const float* kbx = bboxes + ((size_t)b * S_ + key_idx[b * KC + k]) * 4;
        const float* vbx = bboxes + ((size_t)b * S_ + val_idx[b * KC + v]) * 4;
        float k0 = kbx[0], k1 = kbx[1], k2 = kbx[2], k3 = kbx[3];
        float v0 = vbx[0], v1 = vbx[1], v2 = vbx[2], v3 = vbx[3];

        float kcx = (k0 + k2) * 0.5f, kcy = (k1 + k3) * 0.5f;
        float vcx = (v0 + v2) * 0.5f, vcy = (v1 + v3) * 0.5f;
        float dx = vcx - kcx, dy = vcy - kcy;
        float dist = sqrtf(dx * dx + dy * dy + EPSF);
        float angle = atan2f(dy, dx);
        float kh = k3 - k1, vh = v3 - v1, kw = k2 - k0, vw = v2 - v0;
        float h_ov = fmaxf(fminf(k3, v3) - fmaxf(k1, v1), 0.0f);
        float h_align = h_ov / (fminf(kh, vh) + EPSF);
        float v_ov = fmaxf(fminf(k2, v2) - fmaxf(k0, v0), 0.0f);
        float v_align = v_ov / (fminf(kw, vw) + EPSF);
        float area_ratio = (vh * vw) / (kh * kw + EPSF);
        float aspect = (vw / (vh + EPSF)) / (kw / (kh + EPSF));

        float4 sfa = {dx, dy, dist, angle};
        float4 sfb = {h_align, v_align, area_ratio, aspect};

        float4 h2v[8];
        #pragma unroll
        for (int q = 0; q < 8; ++q) h2v[q] = sbs2v[q];

        for (int j = 0; j < 64; ++j) {
            float4 w1a = sWs1T[j * 2], w1b = sWs1T[j * 2 + 1];
            float a = sbs1[j]
                    + sfa.x * w1a.x + sfa.y * w1a.y + sfa.z * w1a.z + sfa.w * w1a.w
                    + sfb.x * w1b.x + sfb.y * w1b.y + sfb.z * w1b.z + sfb.w * w1b.w;
            a = fmaxf(a, 0.0f);
            const float4* w2 = &sWs2v[j * 8];
            #pragma unroll
            for (int q = 0; q < 8; ++q) {
                float4 w = w2[q];
                h2v[q].x += a * w.x; h2v[q].y += a * w.y;
                h2v[q].z += a * w.z; h2v[q].w += a * w.w;
            }
        }

        float c0 = out[gid];
        float score = bf2[0];
        for (int t = 0; t < 16; ++t) {
            float f = sbf1[t] + c0 * sWf1c0[t];
            const float4* w = &sWf1v[t * 8];
            #pragma unroll
            for (int q = 0; q < 8; ++q) {
                float4 ww = w[q];
                f += h2v[q].x * ww.x + h2v[q].y * ww.y
                   + h2v[q].z * ww.z + h2v[q].w * ww.w;
            }
            score += fmaxf(f, 0.0f) * sWf2[t];
        }
        out[gid] = score;
    }
}

// ------------------------------------------------------------------
extern "C" void kernel_launch(void* const* d_in, const int* in_sizes, int n_in,
                              void* d_out, int out_size, void* d_ws, size_t ws_size,
                              hipStream_t stream) {
    const float* seq    = (const float*)d_in[0];
    const float* logits = (const float*)d_in[1];
    const float* bboxes = (const float*)d_in[2];
    const int*   mask   = (const int*)d_in[3];
    const float* Wk   = (const float*)d_in[4];
    const float* bk   = (const float*)d_in[5];
    const float* Wv   = (const float*)d_in[6];
    const float* bv   = (const float*)d_in[7];
    const float* Wbil = (const float*)d_in[8];
    const float* bbil = (const float*)d_in[9];
    const float* Ws1  = (const float*)d_in[10];
    const float* bs1  = (const float*)d_in[11];
    const float* Ws2  = (const float*)d_in[12];
    const float* bs2  = (const float*)d_in[13];
    const float* Wf1  = (const float*)d_in[14];
    const float* bf1  = (const float*)d_in[15];
    const float* Wf2  = (const float*)d_in[16];
    const float* bf2  = (const float*)d_in[17];

    float* out = (float*)d_out;
    char* ws = (char*)d_ws;

    // ws: cnt 4B | (pad) | key_idx 2KB | val_idx 2KB | Wt 6MB | Abf 2MB | reps 2MB
    unsigned* cnt = (unsigned*)ws;
    int* key_idx = (int*)(ws + 64);
    int* val_idx = key_idx + B_ * KC;
    unsigned short* Wt   = (unsigned short*)(ws + 8192);
    unsigned short* Abf  = Wt + (size_t)3 * H_ * H_;
    unsigned short* reps = Abf + (size_t)H_ * H_;

    hipMemsetAsync(cnt, 0, sizeof(unsigned), stream);
    fused_all_kernel<<<NB, 256, 0, stream>>>(
        seq, logits, mask, bboxes,
        Wk, bk, Wv, bv, Wbil, bbil,
        Ws1, bs1, Ws2, bs2, Wf1, bf1, Wf2, bf2,
        Wt, Abf, reps, key_idx, val_idx, cnt, out);
}

// Round 11
// 247.080 us; speedup vs baseline: 1.6098x; 1.6098x over previous
//
#include <hip/hip_runtime.h>
#include <hip/hip_bf16.h>
#include <hip/hip_cooperative_groups.h>
#include <math.h>

namespace cg = cooperative_groups;

#define B_ 4
#define S_ 2048
#define H_ 1024
#define KC 128
#define EPSF 1e-8f
#define NBC 256   // cooperative grid: 1 block/CU

typedef __attribute__((ext_vector_type(8))) short bf16x8;
typedef __attribute__((ext_vector_type(4))) float f32x4;

static __device__ inline unsigned short f2b(float f) {
    unsigned u = __float_as_uint(f);
    return (unsigned short)((u + 0x7fffu + ((u >> 16) & 1u)) >> 16);  // RNE
}

static __device__ inline unsigned long long shflx64(unsigned long long v, int m) {
    int lo = __shfl_xor((int)(unsigned)(v & 0xffffffffull), m, 64);
    int hi = __shfl_xor((int)(unsigned)(v >> 32), m, 64);
    return ((unsigned long long)(unsigned)hi << 32) | (unsigned)lo;
}

#define CROSS_STAGE(k, j) do {                                              \
    const int lm = (j) >> 3;                                                \
    const bool upL  = (((lane) * 8) & (k)) == 0;                            \
    const bool lowr = ((lane) & lm) == 0;                                   \
    _Pragma("unroll")                                                       \
    for (int r = 0; r < 8; ++r) {                                           \
        unsigned long long o = shflx64(e[r], lm);                           \
        e[r] = ((upL == lowr) == (e[r] < o)) ? e[r] : o;                    \
    }                                                                       \
} while (0)

#define INTRA_STAGE(j, k) do {                                              \
    _Pragma("unroll")                                                       \
    for (int r = 0; r < 8; ++r) if (!(r & (j))) {                           \
        bool up = ((((lane) * 8 + r) & (k)) == 0);                          \
        unsigned long long a = e[r], b = e[r | (j)];                        \
        if (up ? (a > b) : (a < b)) { e[r] = b; e[r | (j)] = a; }           \
    }                                                                       \
} while (0)

static __device__ inline void wave_sort512(unsigned long long e[8], int lane) {
    INTRA_STAGE(1, 2);
    INTRA_STAGE(2, 4);  INTRA_STAGE(1, 4);
    INTRA_STAGE(4, 8);  INTRA_STAGE(2, 8);  INTRA_STAGE(1, 8);
    CROSS_STAGE(16, 8);
    INTRA_STAGE(4, 16); INTRA_STAGE(2, 16); INTRA_STAGE(1, 16);
    CROSS_STAGE(32, 16); CROSS_STAGE(32, 8);
    INTRA_STAGE(4, 32); INTRA_STAGE(2, 32); INTRA_STAGE(1, 32);
    CROSS_STAGE(64, 32); CROSS_STAGE(64, 16); CROSS_STAGE(64, 8);
    INTRA_STAGE(4, 64); INTRA_STAGE(2, 64); INTRA_STAGE(1, 64);
    CROSS_STAGE(128, 64); CROSS_STAGE(128, 32); CROSS_STAGE(128, 16);
    CROSS_STAGE(128, 8);
    INTRA_STAGE(4, 128); INTRA_STAGE(2, 128); INTRA_STAGE(1, 128);
    CROSS_STAGE(256, 128); CROSS_STAGE(256, 64); CROSS_STAGE(256, 32);
    CROSS_STAGE(256, 16); CROSS_STAGE(256, 8);
    INTRA_STAGE(4, 256); INTRA_STAGE(2, 256); INTRA_STAGE(1, 256);
    CROSS_STAGE(512, 256); CROSS_STAGE(512, 128); CROSS_STAGE(512, 64);
    CROSS_STAGE(512, 32); CROSS_STAGE(512, 16); CROSS_STAGE(512, 8);
    INTRA_STAGE(4, 512); INTRA_STAGE(2, 512); INTRA_STAGE(1, 512);
}

// Shared device helpers -------------------------------------------------
static __device__ inline void topk_block(
    const float* logits, const int* mask, int blk,
    int* key_idx, int* val_idx, float* out_idx_base,
    unsigned long long* cand, int tid)
{
    const int b   = blk >> 1;
    const int cls = (blk & 1) ? 2 : 1;
    const int wv = tid >> 6, lane = tid & 63;
    unsigned long long e[8];
    #pragma unroll
    for (int r = 0; r < 8; ++r) {
        int s = wv * 512 + lane * 8 + r;
        float l0 = logits[(b * S_ + s) * 3 + 0];
        float l1 = logits[(b * S_ + s) * 3 + 1];
        float l2 = logits[(b * S_ + s) * 3 + 2];
        int pred = 0; float bl = l0;
        if (l1 > bl) { bl = l1; pred = 1; }
        if (l2 > bl) { bl = l2; pred = 2; }
        float c = -1.0f;
        if (pred == cls && mask[b * S_ + s] == 1) {
            double m = (double)bl;
            double e0 = exp((double)l0 - m);
            double e1 = exp((double)l1 - m);
            double e2 = exp((double)l2 - m);
            c = (float)(((cls == 1) ? e1 : e2) / (e0 + e1 + e2));
        }
        unsigned int u = __float_as_uint(c);
        unsigned int mono = (u & 0x80000000u) ? ~u : (u | 0x80000000u);
        e[r] = ((unsigned long long)(~mono) << 32) | (unsigned int)s;
    }
    wave_sort512(e, lane);
    if (lane < 16) {
        #pragma unroll
        for (int r = 0; r < 8; ++r) cand[wv * 128 + lane * 8 + r] = e[r];
    }
    __syncthreads();
    if (wv == 0) {
        #pragma unroll
        for (int r = 0; r < 8; ++r) e[r] = cand[lane * 8 + r];
        wave_sort512(e, lane);
        if (lane < 16) {
            int* idx_out = (blk & 1) ? (val_idx + b * KC) : (key_idx + b * KC);
            float* oidx  = out_idx_base + ((blk & 1) ? B_ * KC : 0) + b * KC;
            #pragma unroll
            for (int r = 0; r < 8; ++r) {
                int sel = (int)(e[r] & 0xffffffffu);
                idx_out[lane * 8 + r] = sel;
                oidx[lane * 8 + r] = (float)sel;
            }
        }
    }
}

struct Params {
    const float *seq, *logits; const int* mask; const float* bboxes;
    const float *Wk, *bk, *Wv, *bv, *Wbil, *bbil;
    const float *Ws1, *bs1, *Ws2, *bs2, *Wf1, *bf1, *Wf2, *bf2;
    unsigned short *Wt, *Abf, *reps;
    int *key_idx, *val_idx;
    float* out;
};

// ======================================================================
// Cooperative single-launch kernel (256 blocks x 256 threads).
// ======================================================================
__global__ __launch_bounds__(256, 2) void fused_all_kernel(Params p) {
    cg::grid_group grid = cg::this_grid();

    __shared__ float tile[32][33];
    __shared__ unsigned long long cand[512];
    __shared__ float4 sWs1T[128];
    __shared__ float  sbs1[64];
    __shared__ float4 sWs2v[512];
    __shared__ float4 sbs2v[8];
    __shared__ float  sWf1c0[16];
    __shared__ float4 sWf1v[128];
    __shared__ float  sbf1[16];
    __shared__ float  sWf2[16];

    const int tid  = threadIdx.x;
    const int bid  = blockIdx.x;
    const int lane = tid & 63;
    const int wv   = tid >> 6;
    const int wgid = bid * 4 + wv;          // 0..1023

    // stage spatial-MLP weights (used in phase 5)
    for (int i = tid; i < 128; i += 256) {
        int j = i >> 1, q = i & 1;
        sWs1T[i] = (float4){p.Ws1[(4*q+0)*64+j], p.Ws1[(4*q+1)*64+j],
                            p.Ws1[(4*q+2)*64+j], p.Ws1[(4*q+3)*64+j]};
    }
    for (int i = tid; i < 64;  i += 256) sbs1[i] = p.bs1[i];
    for (int i = tid; i < 512; i += 256) sWs2v[i] = ((const float4*)p.Ws2)[i];
    if (tid < 8)  sbs2v[tid] = ((const float4*)p.bs2)[tid];
    if (tid < 16) sWf1c0[tid] = p.Wf1[tid];
    for (int i = tid; i < 128; i += 256) {
        int t = i >> 3, q = i & 7;
        sWf1v[i] = (float4){p.Wf1[(1+4*q+0)*16+t], p.Wf1[(1+4*q+1)*16+t],
                            p.Wf1[(1+4*q+2)*16+t], p.Wf1[(1+4*q+3)*16+t]};
    }
    if (tid < 16) sbf1[tid] = p.bf1[tid];
    if (tid < 16) sWf2[tid] = p.Wf2[tid];

    // ===== phase 0: topk (blocks 0..7) | weight transpose (8..255) =====
    if (bid < 8) {
        topk_block(p.logits, p.mask, bid, p.key_idx, p.val_idx,
                   p.out + B_ * KC * KC, cand, tid);
    } else {
        for (int t = bid - 8; t < 3072; t += (NBC - 8)) {
            const int z = t >> 10;
            const int remb = t & 1023;
            const float* Win = (z == 0) ? p.Wk : (z == 1) ? p.Wv : p.Wbil;
            unsigned short* o = p.Wt + (size_t)z * H_ * H_;
            const int n0 = (remb & 31) * 32, k0t = (remb >> 5) * 32;
            const int rr = tid >> 3, cc = (tid & 7) * 4;
            float4 v = *(const float4*)(Win + (size_t)(k0t + rr) * H_ + n0 + cc);
            tile[rr][cc + 0] = v.x; tile[rr][cc + 1] = v.y;
            tile[rr][cc + 2] = v.z; tile[rr][cc + 3] = v.w;
            __syncthreads();
            short4 os;
            os.x = (short)f2b(tile[cc + 0][rr]);
            os.y = (short)f2b(tile[cc + 1][rr]);
            os.z = (short)f2b(tile[cc + 2][rr]);
            os.w = (short)f2b(tile[cc + 3][rr]);
            *(short4*)(o + (size_t)(n0 + rr) * H_ + k0t + cc) = os;
            __syncthreads();
        }
    }
    grid.sync();

    // ===== phase 1: gather + bf16 convert (1024 rows, 1 per wave) ======
    {
        int row = wgid;                       // 0..1023
        int c = lane * 16;
        int b, srow;
        if (row < 512) { b = row >> 7; srow = p.key_idx[row]; }
        else           { b = (row - 512) >> 7; srow = p.val_idx[row - 512]; }
        const float* src = p.seq + ((size_t)b * S_ + srow) * H_ + c;
        #pragma unroll
        for (int q = 0; q < 4; ++q) {
            float4 v = *(const float4*)(src + q * 4);
            short4 o;
            o.x = (short)f2b(v.x); o.y = (short)f2b(v.y);
            o.z = (short)f2b(v.z); o.w = (short)f2b(v.w);
            *(short4*)(p.Abf + (size_t)row * H_ + c + q * 4) = o;
        }
    }
    grid.sync();

    // ===== phase 2: krep/vrep GEMM (2048 16x32 tiles, 2 per wave) ======
    #pragma unroll
    for (int half = 0; half < 2; ++half) {
        const int t = wgid + half * 1024;
        const int m0 = (t >> 5) * 16;
        const int n0 = (t & 31) * 32;
        const bool isv = (m0 >= 512);
        const unsigned short* Wm = p.Wt + (isv ? (size_t)H_ * H_ : 0);
        const float* bias = isv ? p.bv : p.bk;
        const int r = lane & 15, kb = (lane >> 4) * 8;
        f32x4 acc0 = {}, acc1 = {};
        const unsigned short* a0 = p.Abf + (size_t)(m0 + r) * H_ + kb;
        const unsigned short* w0 = Wm + (size_t)(n0 + r) * H_ + kb;
        const unsigned short* w1 = w0 + 16 * H_;
        #pragma unroll 4
        for (int k0 = 0; k0 < H_; k0 += 32) {
            bf16x8 a = *(const bf16x8*)(a0 + k0);
            acc0 = __builtin_amdgcn_mfma_f32_16x16x32_bf16(
                a, *(const bf16x8*)(w0 + k0), acc0, 0, 0, 0);
            acc1 = __builtin_amdgcn_mfma_f32_16x16x32_bf16(
                a, *(const bf16x8*)(w1 + k0), acc1, 0, 0, 0);
        }
        const int orow = (lane >> 4) * 4, ocol = lane & 15;
        #pragma unroll
        for (int g = 0; g < 4; ++g) {
            int m = m0 + orow + g;
            p.reps[(size_t)m * H_ + n0 + ocol]      = f2b(acc0[g] + bias[n0 + ocol]);
            p.reps[(size_t)m * H_ + n0 + 16 + ocol] = f2b(acc1[g] + bias[n0 + 16 + ocol]);
        }
    }
    grid.sync();

    // ===== phase 3: kbt = krep @ WtBil (2048 16x16 tiles, 2/wave) ======
    #pragma unroll
    for (int half = 0; half < 2; ++half) {
        const int t = wgid + half * 1024;
        const int m0 = (t >> 6) * 16;
        const int n0 = (t & 63) * 16;
        const int r = lane & 15, kb = (lane >> 4) * 8;
        f32x4 acc = {};
        const unsigned short* a0 = p.reps + (size_t)(m0 + r) * H_ + kb;
        const unsigned short* w0 = p.Wt + (size_t)2 * H_ * H_
                                 + (size_t)(n0 + r) * H_ + kb;
        #pragma unroll 4
        for (int k0 = 0; k0 < H_; k0 += 32) {
            acc = __builtin_amdgcn_mfma_f32_16x16x32_bf16(
                *(const bf16x8*)(a0 + k0), *(const bf16x8*)(w0 + k0), acc, 0, 0, 0);
        }
        const int orow = (lane >> 4) * 4, ocol = lane & 15;
        #pragma unroll
        for (int g = 0; g < 4; ++g)
            p.Abf[(size_t)(m0 + orow + g) * H_ + n0 + ocol] = f2b(acc[g]);
    }
    grid.sync();

    // ===== phase 4: biaffine (256 16x16 tiles) =========================
    if (wgid < 256) {
        const int b = wgid >> 6, t = wgid & 63;
        const int m0 = (t >> 3) * 16, n0 = (t & 7) * 16;
        const int r = lane & 15, kb = (lane >> 4) * 8;
        f32x4 acc = {};
        const unsigned short* a0 = p.Abf + ((size_t)b * KC + m0 + r) * H_ + kb;
        const unsigned short* w0 = p.reps + (size_t)512 * H_
                                 + ((size_t)b * KC + n0 + r) * H_ + kb;
        #pragma unroll 4
        for (int k0 = 0; k0 < H_; k0 += 32) {
            acc = __builtin_amdgcn_mfma_f32_16x16x32_bf16(
                *(const bf16x8*)(a0 + k0), *(const bf16x8*)(w0 + k0), acc, 0, 0, 0);
        }
        float bb = *p.bbil;
        const int orow = (lane >> 4) * 4, ocol = lane & 15;
        #pragma unroll
        for (int g = 0; g < 4; ++g)
            p.out[((size_t)b * KC + m0 + orow + g) * KC + n0 + ocol] = acc[g] + bb;
    }
    grid.sync();

    // ===== phase 5: spatial + MLPs (512 rows, 2 per block) =============
    {
        const int bk_row = bid * 2 + (tid >> 7);  // 0..511
        const int b = bk_row >> 7;
        const int k = bk_row & 127;
        const int v = tid & 127;
        const int gid = bk_row * 128 + v;

        const float* kbx = p.bboxes + ((size_t)b * S_ + p.key_idx[b * KC + k]) * 4;
        const float* vbx = p.bboxes + ((size_t)b * S_ + p.val_idx[b * KC + v]) * 4;
        float k0 = kbx[0], k1 = kbx[1], k2 = kbx[2], k3 = kbx[3];
        float v0 = vbx[0], v1 = vbx[1], v2 = vbx[2], v3 = vbx[3];

        float kcx = (k0 + k2) * 0.5f, kcy = (k1 + k3) * 0.5f;
        float vcx = (v0 + v2) * 0.5f, vcy = (v1 + v3) * 0.5f;
        float dx = vcx - kcx, dy = vcy - kcy;
        float dist = sqrtf(dx * dx + dy * dy + EPSF);
        float angle = atan2f(dy, dx);
        float kh = k3 - k1, vh = v3 - v1, kw = k2 - k0, vw = v2 - v0;
        float h_ov = fmaxf(fminf(k3, v3) - fmaxf(k1, v1), 0.0f);
        float h_align = h_ov / (fminf(kh, vh) + EPSF);
        float v_ov = fmaxf(fminf(k2, v2) - fmaxf(k0, v0), 0.0f);
        float v_align = v_ov / (fminf(kw, vw) + EPSF);
        float area_ratio = (vh * vw) / (kh * kw + EPSF);
        float aspect = (vw / (vh + EPSF)) / (kw / (kh + EPSF));

        float4 sfa = {dx, dy, dist, angle};
        float4 sfb = {h_align, v_align, area_ratio, aspect};

        float4 h2v[8];
        #pragma unroll
        for (int q = 0; q < 8; ++q) h2v[q] = sbs2v[q];
        for (int j = 0; j < 64; ++j) {
            float4 w1a = sWs1T[j * 2], w1b = sWs1T[j * 2 + 1];
            float a = sbs1[j]
                    + sfa.x * w1a.x + sfa.y * w1a.y + sfa.z * w1a.z + sfa.w * w1a.w
                    + sfb.x * w1b.x + sfb.y * w1b.y + sfb.z * w1b.z + sfb.w * w1b.w;
            a = fmaxf(a, 0.0f);
            const float4* w2 = &sWs2v[j * 8];
            #pragma unroll
            for (int q = 0; q < 8; ++q) {
                float4 w = w2[q];
                h2v[q].x += a * w.x; h2v[q].y += a * w.y;
                h2v[q].z += a * w.z; h2v[q].w += a * w.w;
            }
        }
        float c0 = p.out[gid];
        float score = p.bf2[0];
        for (int t = 0; t < 16; ++t) {
            float f = sbf1[t] + c0 * sWf1c0[t];
            const float4* w = &sWf1v[t * 8];
            #pragma unroll
            for (int q = 0; q < 8; ++q) {
                float4 ww = w[q];
                f += h2v[q].x * ww.x + h2v[q].y * ww.y
                   + h2v[q].z * ww.z + h2v[q].w * ww.w;
            }
            score += fmaxf(f, 0.0f) * sWf2[t];
        }
        p.out[gid] = score;
    }
}

// ======================================================================
// Fallback multi-launch kernels (verified R8 versions).
// ======================================================================
__global__ __launch_bounds__(256) void prep_kernel(
    const float* __restrict__ Wk, const float* __restrict__ Wv,
    const float* __restrict__ Wbil, unsigned short* __restrict__ Wt,
    const float* __restrict__ logits, const int* __restrict__ mask,
    int* __restrict__ key_idx, int* __restrict__ val_idx,
    float* __restrict__ out_idx)
{
    __shared__ float tile[32][33];
    __shared__ unsigned long long cand[512];
    const int tid = threadIdx.x;
    if (blockIdx.x < 3072) {
        const int z = blockIdx.x >> 10;
        const int remb = blockIdx.x & 1023;
        const float* Win = (z == 0) ? Wk : (z == 1) ? Wv : Wbil;
        unsigned short* out = Wt + (size_t)z * H_ * H_;
        const int n0 = (remb & 31) * 32, k0 = (remb >> 5) * 32;
        const int r = tid >> 3, c0 = (tid & 7) * 4;
        float4 v = *(const float4*)(Win + (size_t)(k0 + r) * H_ + n0 + c0);
        tile[r][c0 + 0] = v.x; tile[r][c0 + 1] = v.y;
        tile[r][c0 + 2] = v.z; tile[r][c0 + 3] = v.w;
        __syncthreads();
        short4 o;
        o.x = (short)f2b(tile[c0 + 0][r]);
        o.y = (short)f2b(tile[c0 + 1][r]);
        o.z = (short)f2b(tile[c0 + 2][r]);
        o.w = (short)f2b(tile[c0 + 3][r]);
        *(short4*)(out + (size_t)(n0 + r) * H_ + k0 + c0) = o;
        return;
    }
    topk_block(logits, mask, blockIdx.x - 3072, key_idx, val_idx, out_idx,
               cand, tid);
}

__global__ __launch_bounds__(256) void gatherconv_kernel(
    const float* __restrict__ seq,
    const int* __restrict__ key_idx, const int* __restrict__ val_idx,
    unsigned short* __restrict__ Abf)
{
    const int row = blockIdx.x;
    const int tid = threadIdx.x;
    int b, srow;
    if (row < 512) { b = row >> 7; srow = key_idx[row]; }
    else           { b = (row - 512) >> 7; srow = val_idx[row - 512]; }
    const float* src = seq + ((size_t)b * S_ + srow) * H_ + tid * 4;
    float4 v = *(const float4*)src;
    short4 o;
    o.x = (short)f2b(v.x); o.y = (short)f2b(v.y);
    o.z = (short)f2b(v.z); o.w = (short)f2b(v.w);
    *(short4*)(Abf + (size_t)row * H_ + tid * 4) = o;
}

__global__ __launch_bounds__(64) void gemm_mfma_kernel(
    const unsigned short* __restrict__ A,
    const unsigned short* __restrict__ Wt,
    const float* __restrict__ b0, const float* __restrict__ b1,
    unsigned short* __restrict__ Cout)
{
    const int z = blockIdx.z;
    A    += (size_t)z * 512 * H_;
    Wt   += (size_t)z * H_ * H_;
    Cout += (size_t)z * 512 * H_;
    const float* bias = z ? b1 : b0;
    const int l  = threadIdx.x;
    const int m0 = blockIdx.y * 32;
    const int n0 = blockIdx.x * 32;
    const int r  = l & 15;
    const int kb = (l >> 4) * 8;
    f32x4 acc[2][2] = {};
    const unsigned short* a0 = A + (size_t)(m0 + r) * H_ + kb;
    const unsigned short* a1 = a0 + 16 * H_;
    const unsigned short* w0 = Wt + (size_t)(n0 + r) * H_ + kb;
    const unsigned short* w1 = w0 + 16 * H_;
    #pragma unroll 4
    for (int k0 = 0; k0 < H_; k0 += 32) {
        bf16x8 av[2], bv[2];
        av[0] = *(const bf16x8*)(a0 + k0);
        av[1] = *(const bf16x8*)(a1 + k0);
        bv[0] = *(const bf16x8*)(w0 + k0);
        bv[1] = *(const bf16x8*)(w1 + k0);
        #pragma unroll
        for (int i = 0; i < 2; ++i)
            #pragma unroll
            for (int j = 0; j < 2; ++j)
                acc[i][j] = __builtin_amdgcn_mfma_f32_16x16x32_bf16(
                    av[i], bv[j], acc[i][j], 0, 0, 0);
    }
    const int orow = (l >> 4) * 4, ocol = l & 15;
    #pragma unroll
    for (int i = 0; i < 2; ++i)
        #pragma unroll
        for (int j = 0; j < 2; ++j) {
            int n = n0 + j * 16 + ocol;
            float bv_ = bias ? bias[n] : 0.0f;
            #pragma unroll
            for (int g = 0; g < 4; ++g)
                Cout[(size_t)(m0 + i * 16 + orow + g) * H_ + n] =
                    f2b(acc[i][j][g] + bv_);
        }
}

__global__ __launch_bounds__(64) void biaffine_mfma_kernel(
    const unsigned short* __restrict__ kbt,
    const unsigned short* __restrict__ vrep,
    const float* __restrict__ bbil,
    float* __restrict__ scores)
{
    const int b  = blockIdx.z;
    const int l  = threadIdx.x;
    const int m0 = blockIdx.y * 32;
    const int n0 = blockIdx.x * 32;
    const int r  = l & 15;
    const int kb = (l >> 4) * 8;
    f32x4 acc[2][2] = {};
    const unsigned short* a0 = kbt  + (size_t)(b * KC + m0 + r) * H_ + kb;
    const unsigned short* a1 = a0 + 16 * H_;
    const unsigned short* w0 = vrep + (size_t)(b * KC + n0 + r) * H_ + kb;
    const unsigned short* w1 = w0 + 16 * H_;
    #pragma unroll 4
    for (int k0 = 0; k0 < H_; k0 += 32) {
        bf16x8 av[2], bv[2];
        av[0] = *(const bf16x8*)(a0 + k0);
        av[1] = *(const bf16x8*)(a1 + k0);
        bv[0] = *(const bf16x8*)(w0 + k0);
        bv[1] = *(const bf16x8*)(w1 + k0);
        #pragma unroll
        for (int i = 0; i < 2; ++i)
            #pragma unroll
            for (int j = 0; j < 2; ++j)
                acc[i][j] = __builtin_amdgcn_mfma_f32_16x16x32_bf16(
                    av[i], bv[j], acc[i][j], 0, 0, 0);
    }
    float bb = *bbil;
    const int orow = (l >> 4) * 4, ocol = l & 15;
    #pragma unroll
    for (int i = 0; i < 2; ++i)
        #pragma unroll
        for (int j = 0; j < 2; ++j)
            #pragma unroll
            for (int g = 0; g < 4; ++g)
                scores[((size_t)b * KC + m0 + i * 16 + orow + g) * KC
                       + n0 + j * 16 + ocol] = acc[i][j][g] + bb;
}

__global__ __launch_bounds__(128) void fused_spatial_kernel(
    const float* __restrict__ bboxes,
    const int* __restrict__ key_idx, const int* __restrict__ val_idx,
    const float* __restrict__ Ws1, const float* __restrict__ bs1,
    const float* __restrict__ Ws2, const float* __restrict__ bs2,
    const float* __restrict__ Wf1, const float* __restrict__ bf1,
    const float* __restrict__ Wf2, const float* __restrict__ bf2,
    float* sc)
{
    __shared__ float4 sWs1T[128];
    __shared__ float  sbs1[64];
    __shared__ float4 sWs2v[512];
    __shared__ float4 sbs2v[8];
    __shared__ float  sWf1c0[16];
    __shared__ float4 sWf1v[128];
    __shared__ float  sbf1[16];
    __shared__ float  sWf2[16];
    const int tid = threadIdx.x;
    for (int i = tid; i < 128; i += 128) {
        int j = i >> 1, q = i & 1;
        sWs1T[i] = (float4){Ws1[(4*q+0)*64+j], Ws1[(4*q+1)*64+j],
                            Ws1[(4*q+2)*64+j], Ws1[(4*q+3)*64+j]};
    }
    for (int i = tid; i < 64;  i += 128) sbs1[i] = bs1[i];
    for (int i = tid; i < 512; i += 128) sWs2v[i] = ((const float4*)Ws2)[i];
    if (tid < 8)  sbs2v[tid] = ((const float4*)bs2)[tid];
    if (tid < 16) sWf1c0[tid] = Wf1[tid];
    for (int i = tid; i < 128; i += 128) {
        int t = i >> 3, q = i & 7;
        sWf1v[i] = (float4){Wf1[(1+4*q+0)*16+t], Wf1[(1+4*q+1)*16+t],
                            Wf1[(1+4*q+2)*16+t], Wf1[(1+4*q+3)*16+t]};
    }
    if (tid < 16) sbf1[tid] = bf1[tid];
    if (tid < 16) sWf2[tid] = Wf2[tid];
    __syncthreads();

    const int gid = blockIdx.x * 128 + tid;
    const int b = gid >> 14;
    const int rem = gid & 16383;
    const int k = rem >> 7;
    const int v = rem & 127;

    const float* kbx = bboxes + ((size_t)b * S_ + key_idx[b * KC + k]) * 4;
    const float* vbx = bboxes + ((size_t)b * S_ + val_idx[b * KC + v]) * 4;
    float k0 = kbx[0], k1 = kbx[1], k2 = kbx[2], k3 = kbx[3];
    float v0 = vbx[0], v1 = vbx[1], v2 = vbx[2], v3 = vbx[3];
    float kcx = (k0 + k2) * 0.5f, kcy = (k1 + k3) * 0.5f;
    float vcx = (v0 + v2) * 0.5f, vcy = (v1 + v3) * 0.5f;
    float dx = vcx - kcx, dy = vcy - kcy;
    float dist = sqrtf(dx * dx + dy * dy + EPSF);
    float angle = atan2f(dy, dx);
    float kh = k3 - k1, vh = v3 - v1, kw = k2 - k0, vw = v2 - v0;
    float h_ov = fmaxf(fminf(k3, v3) - fmaxf(k1, v1), 0.0f);
    float h_align = h_ov / (fminf(kh, vh) + EPSF);
    float v_ov = fmaxf(fminf(k2, v2) - fmaxf(k0, v0), 0.0f);
    float v_align = v_ov / (fminf(kw, vw) + EPSF);
    float area_ratio = (vh * vw) / (kh * kw + EPSF);
    float aspect = (vw / (vh + EPSF)) / (kw / (kh + EPSF));
    float4 sfa = {dx, dy, dist, angle};
    float4 sfb = {h_align, v_align, area_ratio, aspect};
    float4 h2v[8];
    #pragma unroll
    for (int q = 0; q < 8; ++q) h2v[q] = sbs2v[q];
    for (int j = 0; j < 64; ++j) {
        float4 w1a = sWs1T[j * 2], w1b = sWs1T[j * 2 + 1];
        float a = sbs1[j]
                + sfa.x * w1a.x + sfa.y * w1a.y + sfa.z * w1a.z + sfa.w * w1a.w
                + sfb.x * w1b.x + sfb.y * w1b.y + sfb.z * w1b.z + sfb.w * w1b.w;
        a = fmaxf(a, 0.0f);
        const float4* w2 = &sWs2v[j * 8];
        #pragma unroll
        for (int q = 0; q < 8; ++q) {
            float4 w = w2[q];
            h2v[q].x += a * w.x; h2v[q].y += a * w.y;
            h2v[q].z += a * w.z; h2v[q].w += a * w.w;
        }
    }
    float c0 = sc[gid];
    float score = bf2[0];
    for (int t = 0; t < 16; ++t) {
        float f = sbf1[t] + c0 * sWf1c0[t];
        const float4* w = &sWf1v[t * 8];
        #pragma unroll
        for (int q = 0; q < 8; ++q) {
            float4 ww = w[q];
            f += h2v[q].x * ww.x + h2v[q].y * ww.y
               + h2v[q].z * ww.z + h2v[q].w * ww.w;
        }
        score += fmaxf(f, 0.0f) * sWf2[t];
    }
    sc[gid] = score;
}

// ------------------------------------------------------------------
extern "C" void kernel_launch(void* const* d_in, const int* in_sizes, int n_in,
                              void* d_out, int out_size, void* d_ws, size_t ws_size,
                              hipStream_t stream) {
    char* ws = (char*)d_ws;

    Params p;
    p.seq    = (const float*)d_in[0];
    p.logits = (const float*)d_in[1];
    p.bboxes = (const float*)d_in[2];
    p.mask   = (const int*)d_in[3];
    p.Wk   = (const float*)d_in[4];
    p.bk   = (const float*)d_in[5];
    p.Wv   = (const float*)d_in[6];
    p.bv   = (const float*)d_in[7];
    p.Wbil = (const float*)d_in[8];
    p.bbil = (const float*)d_in[9];
    p.Ws1  = (const float*)d_in[10];
    p.bs1  = (const float*)d_in[11];
    p.Ws2  = (const float*)d_in[12];
    p.bs2  = (const float*)d_in[13];
    p.Wf1  = (const float*)d_in[14];
    p.bf1  = (const float*)d_in[15];
    p.Wf2  = (const float*)d_in[16];
    p.bf2  = (const float*)d_in[17];
    p.key_idx = (int*)(ws + 64);
    p.val_idx = p.key_idx + B_ * KC;
    p.Wt   = (unsigned short*)(ws + 8192);
    p.Abf  = p.Wt + (size_t)3 * H_ * H_;
    p.reps = p.Abf + (size_t)H_ * H_;
    p.out  = (float*)d_out;

    // Decide cooperative-launch viability (host queries only; no stream ops).
    int coop_ok = 0;
    {
        int dev = 0;
        hipGetDevice(&dev);
        int attr = 0;
        hipDeviceGetAttribute(&attr, hipDeviceAttributeCooperativeLaunch, dev);
        if (attr) {
            int numCU = 0;
            hipDeviceGetAttribute(&numCU, hipDeviceAttributeMultiprocessorCount, dev);
            int maxB = 0;
            hipError_t e = hipOccupancyMaxActiveBlocksPerMultiprocessor(
                &maxB, fused_all_kernel, 256, 0);
            if (e == hipSuccess && (long)maxB * numCU >= NBC) coop_ok = 1;
        }
    }

    if (coop_ok) {
        void* args[] = { &p };
        hipError_t e = hipLaunchCooperativeKernel((void*)fused_all_kernel,
                                                  dim3(NBC), dim3(256), args,
                                                  0, stream);
        if (e == hipSuccess) return;
    }

    // ---------------- fallback: verified multi-launch path ----------------
    prep_kernel<<<3080, 256, 0, stream>>>(p.Wk, p.Wv, p.Wbil, p.Wt,
                                          p.logits, p.mask, p.key_idx, p.val_idx,
                                          p.out + B_ * KC * KC);
    gatherconv_kernel<<<1024, 256, 0, stream>>>(p.seq, p.key_idx, p.val_idx, p.Abf);
    gemm_mfma_kernel<<<dim3(32, 16, 2), 64, 0, stream>>>(
        p.Abf, p.Wt, p.bk, p.bv, p.reps);
    gemm_mfma_kernel<<<dim3(32, 16, 1), 64, 0, stream>>>(
        p.reps, p.Wt + (size_t)2 * H_ * H_, nullptr, nullptr, p.Abf);
    biaffine_mfma_kernel<<<dim3(4, 4, B_), 64, 0, stream>>>(
        p.Abf, p.reps + (size_t)512 * H_, p.bbil, p.out);
    fused_spatial_kernel<<<512, 128, 0, stream>>>(
        p.bboxes, p.key_idx, p.val_idx,
        p.Ws1, p.bs1, p.Ws2, p.bs2, p.Wf1, p.bf1, p.Wf2, p.bf2, p.out);
}

// Round 12
// 183.774 us; speedup vs baseline: 2.1643x; 1.3445x over previous
//
#include <hip/hip_runtime.h>
#include <hip/hip_bf16.h>
#include <math.h>

#define B_ 4
#define S_ 2048
#define H_ 1024
#define KC 128
#define EPSF 1e-8f

typedef __attribute__((ext_vector_type(8))) short bf16x8;
typedef __attribute__((ext_vector_type(4))) float f32x4;

static __device__ inline unsigned short f2b(float f) {
    unsigned u = __float_as_uint(f);
    return (unsigned short)((u + 0x7fffu + ((u >> 16) & 1u)) >> 16);  // RNE
}

static __device__ inline unsigned long long shflx64(unsigned long long v, int m) {
    int lo = __shfl_xor((int)(unsigned)(v & 0xffffffffull), m, 64);
    int hi = __shfl_xor((int)(unsigned)(v >> 32), m, 64);
    return ((unsigned long long)(unsigned)hi << 32) | (unsigned)lo;
}

#define CROSS_STAGE(k, j) do {                                              \
    const int lm = (j) >> 3;                                                \
    const bool upL  = (((lane) * 8) & (k)) == 0;                            \
    const bool lowr = ((lane) & lm) == 0;                                   \
    _Pragma("unroll")                                                       \
    for (int r = 0; r < 8; ++r) {                                           \
        unsigned long long o = shflx64(e[r], lm);                           \
        e[r] = ((upL == lowr) == (e[r] < o)) ? e[r] : o;                    \
    }                                                                       \
} while (0)

#define INTRA_STAGE(j, k) do {                                              \
    _Pragma("unroll")                                                       \
    for (int r = 0; r < 8; ++r) if (!(r & (j))) {                           \
        bool up = ((((lane) * 8 + r) & (k)) == 0);                          \
        unsigned long long a = e[r], b = e[r | (j)];                        \
        if (up ? (a > b) : (a < b)) { e[r] = b; e[r | (j)] = a; }           \
    }                                                                       \
} while (0)

static __device__ inline void wave_sort512(unsigned long long e[8], int lane) {
    INTRA_STAGE(1, 2);
    INTRA_STAGE(2, 4);  INTRA_STAGE(1, 4);
    INTRA_STAGE(4, 8);  INTRA_STAGE(2, 8);  INTRA_STAGE(1, 8);
    CROSS_STAGE(16, 8);
    INTRA_STAGE(4, 16); INTRA_STAGE(2, 16); INTRA_STAGE(1, 16);
    CROSS_STAGE(32, 16); CROSS_STAGE(32, 8);
    INTRA_STAGE(4, 32); INTRA_STAGE(2, 32); INTRA_STAGE(1, 32);
    CROSS_STAGE(64, 32); CROSS_STAGE(64, 16); CROSS_STAGE(64, 8);
    INTRA_STAGE(4, 64); INTRA_STAGE(2, 64); INTRA_STAGE(1, 64);
    CROSS_STAGE(128, 64); CROSS_STAGE(128, 32); CROSS_STAGE(128, 16);
    CROSS_STAGE(128, 8);
    INTRA_STAGE(4, 128); INTRA_STAGE(2, 128); INTRA_STAGE(1, 128);
    CROSS_STAGE(256, 128); CROSS_STAGE(256, 64); CROSS_STAGE(256, 32);
    CROSS_STAGE(256, 16); CROSS_STAGE(256, 8);
    INTRA_STAGE(4, 256); INTRA_STAGE(2, 256); INTRA_STAGE(1, 256);
    CROSS_STAGE(512, 256); CROSS_STAGE(512, 128); CROSS_STAGE(512, 64);
    CROSS_STAGE(512, 32); CROSS_STAGE(512, 16); CROSS_STAGE(512, 8);
    INTRA_STAGE(4, 512); INTRA_STAGE(2, 512); INTRA_STAGE(1, 512);
}

static __device__ inline void topk_block(
    const float* logits, const int* mask, int blk,
    int* key_idx, int* val_idx, float* out_idx_base,
    unsigned long long* cand, int tid)
{
    const int b   = blk >> 1;
    const int cls = (blk & 1) ? 2 : 1;
    const int wv = tid >> 6, lane = tid & 63;
    unsigned long long e[8];
    #pragma unroll
    for (int r = 0; r < 8; ++r) {
        int s = wv * 512 + lane * 8 + r;
        float l0 = logits[(b * S_ + s) * 3 + 0];
        float l1 = logits[(b * S_ + s) * 3 + 1];
        float l2 = logits[(b * S_ + s) * 3 + 2];
        int pred = 0; float bl = l0;
        if (l1 > bl) { bl = l1; pred = 1; }
        if (l2 > bl) { bl = l2; pred = 2; }
        float c = -1.0f;
        if (pred == cls && mask[b * S_ + s] == 1) {
            double m = (double)bl;
            double e0 = exp((double)l0 - m);
            double e1 = exp((double)l1 - m);
            double e2 = exp((double)l2 - m);
            c = (float)(((cls == 1) ? e1 : e2) / (e0 + e1 + e2));
        }
        unsigned int u = __float_as_uint(c);
        unsigned int mono = (u & 0x80000000u) ? ~u : (u | 0x80000000u);
        e[r] = ((unsigned long long)(~mono) << 32) | (unsigned int)s;
    }
    wave_sort512(e, lane);
    if (lane < 16) {
        #pragma unroll
        for (int r = 0; r < 8; ++r) cand[wv * 128 + lane * 8 + r] = e[r];
    }
    __syncthreads();
    if (wv == 0) {
        #pragma unroll
        for (int r = 0; r < 8; ++r) e[r] = cand[lane * 8 + r];
        wave_sort512(e, lane);
        if (lane < 16) {
            int* idx_out = (blk & 1) ? (val_idx + b * KC) : (key_idx + b * KC);
            float* oidx  = out_idx_base + ((blk & 1) ? B_ * KC : 0) + b * KC;
            #pragma unroll
            for (int r = 0; r < 8; ++r) {
                int sel = (int)(e[r] & 0xffffffffu);
                idx_out[lane * 8 + r] = sel;
                oidx[lane * 8 + r] = (float)sel;
            }
        }
    }
}

// ------------------------------------------------------------------
// L1: topk (blocks 3072..3079) + weight transpose/convert (0..3071).
// ------------------------------------------------------------------
__global__ __launch_bounds__(256) void prep_kernel(
    const float* __restrict__ Wk, const float* __restrict__ Wv,
    const float* __restrict__ Wbil, unsigned short* __restrict__ Wt,
    const float* __restrict__ logits, const int* __restrict__ mask,
    int* __restrict__ key_idx, int* __restrict__ val_idx,
    float* __restrict__ out_idx)
{
    __shared__ float tile[32][33];
    __shared__ unsigned long long cand[512];
    const int tid = threadIdx.x;
    if (blockIdx.x < 3072) {
        const int z = blockIdx.x >> 10;
        const int remb = blockIdx.x & 1023;
        const float* Win = (z == 0) ? Wk : (z == 1) ? Wv : Wbil;
        unsigned short* out = Wt + (size_t)z * H_ * H_;
        const int n0 = (remb & 31) * 32, k0 = (remb >> 5) * 32;
        const int r = tid >> 3, c0 = (tid & 7) * 4;
        float4 v = *(const float4*)(Win + (size_t)(k0 + r) * H_ + n0 + c0);
        tile[r][c0 + 0] = v.x; tile[r][c0 + 1] = v.y;
        tile[r][c0 + 2] = v.z; tile[r][c0 + 3] = v.w;
        __syncthreads();
        short4 o;
        o.x = (short)f2b(tile[c0 + 0][r]);
        o.y = (short)f2b(tile[c0 + 1][r]);
        o.z = (short)f2b(tile[c0 + 2][r]);
        o.w = (short)f2b(tile[c0 + 3][r]);
        *(short4*)(out + (size_t)(n0 + r) * H_ + k0 + c0) = o;
        return;
    }
    topk_block(logits, mask, blockIdx.x - 3072, key_idx, val_idx, out_idx,
               cand, tid);
}

// ------------------------------------------------------------------
// L2: 64 blocks x 512 thr. bid<32: keys (gather->LDS, krep->LDS, kbt->global).
// bid>=32: vals (gather->LDS, vrep->global). XOR-swizzled LDS (G4).
// ------------------------------------------------------------------
__global__ __launch_bounds__(512, 1) void rep_kernel(
    const float* __restrict__ seq,
    const int* __restrict__ key_idx, const int* __restrict__ val_idx,
    const unsigned short* __restrict__ Wt,
    const float* __restrict__ bk, const float* __restrict__ bv,
    unsigned short* __restrict__ kbt, unsigned short* __restrict__ vrep)
{
    __shared__ __align__(16) char AsB[16 * 2048];   // 16 rows x 1024 bf16
    __shared__ __align__(16) char BsB[16 * 2048];   // krep panel (keys only)

    const int tid = threadIdx.x;
    const bool isKey = blockIdx.x < 32;
    const int m0 = (blockIdx.x & 31) * 16;
    const int* idx = isKey ? key_idx : val_idx;
    const unsigned short* W1 = Wt + (isKey ? (size_t)0 : (size_t)H_ * H_);
    const float* bias1 = isKey ? bk : bv;

    // Step A: gather 16 seq rows, convert to bf16, store swizzled.
    {
        const int row = tid >> 5;            // 0..15
        const int c0 = (tid & 31) * 32;      // 32 floats per thread
        const int gm = m0 + row;
        const float* src = seq + ((size_t)(gm >> 7) * S_ + idx[gm]) * H_ + c0;
        #pragma unroll
        for (int q = 0; q < 4; ++q) {
            float4 va = *(const float4*)(src + q * 8);
            float4 vb = *(const float4*)(src + q * 8 + 4);
            bf16x8 o;
            o[0] = (short)f2b(va.x); o[1] = (short)f2b(va.y);
            o[2] = (short)f2b(va.z); o[3] = (short)f2b(va.w);
            o[4] = (short)f2b(vb.x); o[5] = (short)f2b(vb.y);
            o[6] = (short)f2b(vb.z); o[7] = (short)f2b(vb.w);
            int byte = (row * 2048 + (c0 + q * 8) * 2) ^ ((row & 7) << 4);
            *(bf16x8*)(AsB + byte) = o;
        }
    }
    __syncthreads();

    const int lane = tid & 63, wv = tid >> 6;      // 8 waves
    const int r = lane & 15, kq = (lane >> 4) * 8;
    const int orow = (lane >> 4) * 4, ocol = lane & 15;

    // Step B: rep = As @ W1^T-layout + bias. Waves cover n = wv*128 .. +128.
    #pragma unroll
    for (int j = 0; j < 4; ++j) {
        const int n0 = wv * 128 + j * 32;
        f32x4 acc0 = {}, acc1 = {};
        const unsigned short* w0 = W1 + (size_t)(n0 + r) * H_ + kq;
        const unsigned short* w1 = w0 + 16 * H_;
        #pragma unroll 4
        for (int k0 = 0; k0 < H_; k0 += 32) {
            bf16x8 a = *(const bf16x8*)(AsB +
                ((r * 2048 + (k0 + kq) * 2) ^ ((r & 7) << 4)));
            acc0 = __builtin_amdgcn_mfma_f32_16x16x32_bf16(
                a, *(const bf16x8*)(w0 + k0), acc0, 0, 0, 0);
            acc1 = __builtin_amdgcn_mfma_f32_16x16x32_bf16(
                a, *(const bf16x8*)(w1 + k0), acc1, 0, 0, 0);
        }
        if (isKey) {
            #pragma unroll
            for (int g = 0; g < 4; ++g) {
                int mr = orow + g;
                *(unsigned short*)(BsB + ((mr * 2048 + (n0 + ocol) * 2)
                                          ^ ((mr & 7) << 4)))
                    = f2b(acc0[g] + bias1[n0 + ocol]);
                *(unsigned short*)(BsB + ((mr * 2048 + (n0 + 16 + ocol) * 2)
                                          ^ ((mr & 7) << 4)))
                    = f2b(acc1[g] + bias1[n0 + 16 + ocol]);
            }
        } else {
            #pragma unroll
            for (int g = 0; g < 4; ++g) {
                int m = m0 + orow + g;
                vrep[(size_t)m * H_ + n0 + ocol]
                    = f2b(acc0[g] + bias1[n0 + ocol]);
                vrep[(size_t)m * H_ + n0 + 16 + ocol]
                    = f2b(acc1[g] + bias1[n0 + 16 + ocol]);
            }
        }
    }
    if (!isKey) return;
    __syncthreads();

    // Step C: kbt = krep(LDS) @ WtBil -> global (no bias).
    const unsigned short* WB = Wt + (size_t)2 * H_ * H_;
    #pragma unroll
    for (int j = 0; j < 4; ++j) {
        const int n0 = wv * 128 + j * 32;
        f32x4 acc0 = {}, acc1 = {};
        const unsigned short* w0 = WB + (size_t)(n0 + r) * H_ + kq;
        const unsigned short* w1 = w0 + 16 * H_;
        #pragma unroll 4
        for (int k0 = 0; k0 < H_; k0 += 32) {
            bf16x8 a = *(const bf16x8*)(BsB +
                ((r * 2048 + (k0 + kq) * 2) ^ ((r & 7) << 4)));
            acc0 = __builtin_amdgcn_mfma_f32_16x16x32_bf16(
                a, *(const bf16x8*)(w0 + k0), acc0, 0, 0, 0);
            acc1 = __builtin_amdgcn_mfma_f32_16x16x32_bf16(
                a, *(const bf16x8*)(w1 + k0), acc1, 0, 0, 0);
        }
        #pragma unroll
        for (int g = 0; g < 4; ++g) {
            int m = m0 + orow + g;
            kbt[(size_t)m * H_ + n0 + ocol]      = f2b(acc0[g]);
            kbt[(size_t)m * H_ + n0 + 16 + ocol] = f2b(acc1[g]);
        }
    }
}

// ------------------------------------------------------------------
// L3: biaffine (4-wave K-split MFMA) fused with spatial MLP.
// 256 blocks x 256 thr; block = (b, 16x16 biaffine tile); 1 elem/thread.
// ------------------------------------------------------------------
__global__ __launch_bounds__(256) void biasp_kernel(
    const unsigned short* __restrict__ kbt,
    const unsigned short* __restrict__ vrep,
    const float* __restrict__ bbil, const float* __restrict__ bboxes,
    const int* __restrict__ key_idx, const int* __restrict__ val_idx,
    const float* __restrict__ Ws1, const float* __restrict__ bs1,
    const float* __restrict__ Ws2, const float* __restrict__ bs2,
    const float* __restrict__ Wf1, const float* __restrict__ bf1,
    const float* __restrict__ Wf2, const float* __restrict__ bf2,
    float* __restrict__ out)
{
    __shared__ float part[4][16][16];
    __shared__ float4 sWs1T[128];
    __shared__ float  sbs1[64];
    __shared__ float4 sWs2v[512];
    __shared__ float4 sbs2v[8];
    __shared__ float  sWf1c0[16];
    __shared__ float4 sWf1v[128];
    __shared__ float  sbf1[16];
    __shared__ float  sWf2[16];

    const int tid = threadIdx.x;
    for (int i = tid; i < 128; i += 256) {
        int j = i >> 1, q = i & 1;
        sWs1T[i] = (float4){Ws1[(4*q+0)*64+j], Ws1[(4*q+1)*64+j],
                            Ws1[(4*q+2)*64+j], Ws1[(4*q+3)*64+j]};
    }
    for (int i = tid; i < 64;  i += 256) sbs1[i] = bs1[i];
    for (int i = tid; i < 512; i += 256) sWs2v[i] = ((const float4*)Ws2)[i];
    if (tid < 8)  sbs2v[tid] = ((const float4*)bs2)[tid];
    if (tid < 16) sWf1c0[tid] = Wf1[tid];
    for (int i = tid; i < 128; i += 256) {
        int t = i >> 3, q = i & 7;
        sWf1v[i] = (float4){Wf1[(1+4*q+0)*16+t], Wf1[(1+4*q+1)*16+t],
                            Wf1[(1+4*q+2)*16+t], Wf1[(1+4*q+3)*16+t]};
    }
    if (tid < 16) sbf1[tid] = bf1[tid];
    if (tid < 16) sWf2[tid] = Wf2[tid];

    const int b = blockIdx.x >> 6;
    const int t = blockIdx.x & 63;
    const int m0 = (t >> 3) * 16, n0 = (t & 7) * 16;
    const int lane = tid & 63, wv = tid >> 6;
    const int r = lane & 15, kq = (lane >> 4) * 8;

    f32x4 acc = {};
    const unsigned short* a0 = kbt  + (size_t)(b * KC + m0 + r) * H_ + kq;
    const unsigned short* w0 = vrep + (size_t)(b * KC + n0 + r) * H_ + kq;
    #pragma unroll
    for (int kk = 0; kk < 8; ++kk) {
        int k0 = wv * 256 + kk * 32;
        acc = __builtin_amdgcn_mfma_f32_16x16x32_bf16(
            *(const bf16x8*)(a0 + k0), *(const bf16x8*)(w0 + k0), acc, 0, 0, 0);
    }
    const int orow = (lane >> 4) * 4, ocol = lane & 15;
    #pragma unroll
    for (int g = 0; g < 4; ++g) part[wv][orow + g][ocol] = acc[g];
    __syncthreads();

    const int kl = tid >> 4, vl = tid & 15;
    float c0 = part[0][kl][vl] + part[1][kl][vl]
             + part[2][kl][vl] + part[3][kl][vl] + bbil[0];
    const int kg = m0 + kl, vg = n0 + vl;

    const float* kbx = bboxes + ((size_t)b * S_ + key_idx[b * KC + kg]) * 4;
    const float* vbx = bboxes + ((size_t)b * S_ + val_idx[b * KC + vg]) * 4;
    float k0_ = kbx[0], k1_ = kbx[1], k2_ = kbx[2], k3_ = kbx[3];
    float v0_ = vbx[0], v1_ = vbx[1], v2_ = vbx[2], v3_ = vbx[3];

    float kcx = (k0_ + k2_) * 0.5f, kcy = (k1_ + k3_) * 0.5f;
    float vcx = (v0_ + v2_) * 0.5f, vcy = (v1_ + v3_) * 0.5f;
    float dx = vcx - kcx, dy = vcy - kcy;
    float dist = sqrtf(dx * dx + dy * dy + EPSF);
    float angle = atan2f(dy, dx);
    float kh = k3_ - k1_, vh = v3_ - v1_, kw = k2_ - k0_, vw = v2_ - v0_;
    float h_ov = fmaxf(fminf(k3_, v3_) - fmaxf(k1_, v1_), 0.0f);
    float h_align = h_ov / (fminf(kh, vh) + EPSF);
    float v_ov = fmaxf(fminf(k2_, v2_) - fmaxf(k0_, v0_), 0.0f);
    float v_align = v_ov / (fminf(kw, vw) + EPSF);
    float area_ratio = (vh * vw) / (kh * kw + EPSF);
    float aspect = (vw / (vh + EPSF)) / (kw / (kh + EPSF));

    float4 sfa = {dx, dy, dist, angle};
    float4 sfb = {h_align, v_align, area_ratio, aspect};

    float4 h2v[8];
    #pragma unroll
    for (int q = 0; q < 8; ++q) h2v[q] = sbs2v[q];
    for (int j = 0; j < 64; ++j) {
        float4 w1a = sWs1T[j * 2], w1b = sWs1T[j * 2 + 1];
        float a = sbs1[j]
                + sfa.x * w1a.x + sfa.y * w1a.y + sfa.z * w1a.z + sfa.w * w1a.w
                + sfb.x * w1b.x + sfb.y * w1b.y + sfb.z * w1b.z + sfb.w * w1b.w;
        a = fmaxf(a, 0.0f);
        const float4* w2 = &sWs2v[j * 8];
        #pragma unroll
        for (int q = 0; q < 8; ++q) {
            float4 w = w2[q];
            h2v[q].x += a * w.x; h2v[q].y += a * w.y;
            h2v[q].z += a * w.z; h2v[q].w += a * w.w;
        }
    }
    float score = bf2[0];
    for (int tt = 0; tt < 16; ++tt) {
        float f = sbf1[tt] + c0 * sWf1c0[tt];
        const float4* w = &sWf1v[tt * 8];
        #pragma unroll
        for (int q = 0; q < 8; ++q) {
            float4 ww = w[q];
            f += h2v[q].x * ww.x + h2v[q].y * ww.y
               + h2v[q].z * ww.z + h2v[q].w * ww.w;
        }
        score += fmaxf(f, 0.0f) * sWf2[tt];
    }
    out[((size_t)b * KC + kg) * KC + vg] = score;
}

// ------------------------------------------------------------------
extern "C" void kernel_launch(void* const* d_in, const int* in_sizes, int n_in,
                              void* d_out, int out_size, void* d_ws, size_t ws_size,
                              hipStream_t stream) {
    const float* seq    = (const float*)d_in[0];
    const float* logits = (const float*)d_in[1];
    const float* bboxes = (const float*)d_in[2];
    const int*   mask   = (const int*)d_in[3];
    const float* Wk   = (const float*)d_in[4];
    const float* bk   = (const float*)d_in[5];
    const float* Wv   = (const float*)d_in[6];
    const float* bv   = (const float*)d_in[7];
    const float* Wbil = (const float*)d_in[8];
    const float* bbil = (const float*)d_in[9];
    const float* Ws1  = (const float*)d_in[10];
    const float* bs1  = (const float*)d_in[11];
    const float* Ws2  = (const float*)d_in[12];
    const float* bs2  = (const float*)d_in[13];
    const float* Wf1  = (const float*)d_in[14];
    const float* bf1  = (const float*)d_in[15];
    const float* Wf2  = (const float*)d_in[16];
    const float* bf2  = (const float*)d_in[17];

    float* out = (float*)d_out;
    char* ws = (char*)d_ws;

    // ws: idx @64 | Wt 6MB @8192 | kbt 1MB | vrep 1MB
    int* key_idx = (int*)(ws + 64);
    int* val_idx = key_idx + B_ * KC;
    unsigned short* Wt   = (unsigned short*)(ws + 8192);
    unsigned short* kbt  = Wt + (size_t)3 * H_ * H_;
    unsigned short* vrep = kbt + (size_t)512 * H_;

    prep_kernel<<<3080, 256, 0, stream>>>(Wk, Wv, Wbil, Wt,
                                          logits, mask, key_idx, val_idx,
                                          out + B_ * KC * KC);
    rep_kernel<<<64, 512, 0, stream>>>(seq, key_idx, val_idx, Wt,
                                       bk, bv, kbt, vrep);
    biasp_kernel<<<256, 256, 0, stream>>>(kbt, vrep, bbil, bboxes,
                                          key_idx, val_idx,
                                          Ws1, bs1, Ws2, bs2,
                                          Wf1, bf1, Wf2, bf2, out);
}

// Round 13
// 106.149 us; speedup vs baseline: 3.7471x; 1.7313x over previous
//
#include <hip/hip_runtime.h>
#include <hip/hip_bf16.h>
#include <math.h>

#define B_ 4
#define S_ 2048
#define H_ 1024
#define KC 128
#define EPSF 1e-8f

typedef __attribute__((ext_vector_type(8))) short bf16x8;
typedef __attribute__((ext_vector_type(4))) float f32x4;

static __device__ inline unsigned short f2b(float f) {
    unsigned u = __float_as_uint(f);
    return (unsigned short)((u + 0x7fffu + ((u >> 16) & 1u)) >> 16);  // RNE
}

static __device__ inline unsigned long long shflx64(unsigned long long v, int m) {
    int lo = __shfl_xor((int)(unsigned)(v & 0xffffffffull), m, 64);
    int hi = __shfl_xor((int)(unsigned)(v >> 32), m, 64);
    return ((unsigned long long)(unsigned)hi << 32) | (unsigned)lo;
}

#define CROSS_STAGE(k, j) do {                                              \
    const int lm = (j) >> 3;                                                \
    const bool upL  = (((lane) * 8) & (k)) == 0;                            \
    const bool lowr = ((lane) & lm) == 0;                                   \
    _Pragma("unroll")                                                       \
    for (int r = 0; r < 8; ++r) {                                           \
        unsigned long long o = shflx64(e[r], lm);                           \
        e[r] = ((upL == lowr) == (e[r] < o)) ? e[r] : o;                    \
    }                                                                       \
} while (0)

#define INTRA_STAGE(j, k) do {                                              \
    _Pragma("unroll")                                                       \
    for (int r = 0; r < 8; ++r) if (!(r & (j))) {                           \
        bool up = ((((lane) * 8 + r) & (k)) == 0);                          \
        unsigned long long a = e[r], b = e[r | (j)];                        \
        if (up ? (a > b) : (a < b)) { e[r] = b; e[r | (j)] = a; }           \
    }                                                                       \
} while (0)

static __device__ inline void wave_sort512(unsigned long long e[8], int lane) {
    INTRA_STAGE(1, 2);
    INTRA_STAGE(2, 4);  INTRA_STAGE(1, 4);
    INTRA_STAGE(4, 8);  INTRA_STAGE(2, 8);  INTRA_STAGE(1, 8);
    CROSS_STAGE(16, 8);
    INTRA_STAGE(4, 16); INTRA_STAGE(2, 16); INTRA_STAGE(1, 16);
    CROSS_STAGE(32, 16); CROSS_STAGE(32, 8);
    INTRA_STAGE(4, 32); INTRA_STAGE(2, 32); INTRA_STAGE(1, 32);
    CROSS_STAGE(64, 32); CROSS_STAGE(64, 16); CROSS_STAGE(64, 8);
    INTRA_STAGE(4, 64); INTRA_STAGE(2, 64); INTRA_STAGE(1, 64);
    CROSS_STAGE(128, 64); CROSS_STAGE(128, 32); CROSS_STAGE(128, 16);
    CROSS_STAGE(128, 8);
    INTRA_STAGE(4, 128); INTRA_STAGE(2, 128); INTRA_STAGE(1, 128);
    CROSS_STAGE(256, 128); CROSS_STAGE(256, 64); CROSS_STAGE(256, 32);
    CROSS_STAGE(256, 16); CROSS_STAGE(256, 8);
    INTRA_STAGE(4, 256); INTRA_STAGE(2, 256); INTRA_STAGE(1, 256);
    CROSS_STAGE(512, 256); CROSS_STAGE(512, 128); CROSS_STAGE(512, 64);
    CROSS_STAGE(512, 32); CROSS_STAGE(512, 16); CROSS_STAGE(512, 8);
    INTRA_STAGE(4, 512); INTRA_STAGE(2, 512); INTRA_STAGE(1, 512);
}

static __device__ inline void topk_block(
    const float* logits, const int* mask, int blk,
    int* key_idx, int* val_idx, float* out_idx_base,
    unsigned long long* cand, int tid)
{
    const int b   = blk >> 1;
    const int cls = (blk & 1) ? 2 : 1;
    const int wv = tid >> 6, lane = tid & 63;
    unsigned long long e[8];
    #pragma unroll
    for (int r = 0; r < 8; ++r) {
        int s = wv * 512 + lane * 8 + r;
        float l0 = logits[(b * S_ + s) * 3 + 0];
        float l1 = logits[(b * S_ + s) * 3 + 1];
        float l2 = logits[(b * S_ + s) * 3 + 2];
        int pred = 0; float bl = l0;
        if (l1 > bl) { bl = l1; pred = 1; }
        if (l2 > bl) { bl = l2; pred = 2; }
        float c = -1.0f;
        if (pred == cls && mask[b * S_ + s] == 1) {
            double m = (double)bl;
            double e0 = exp((double)l0 - m);
            double e1 = exp((double)l1 - m);
            double e2 = exp((double)l2 - m);
            c = (float)(((cls == 1) ? e1 : e2) / (e0 + e1 + e2));
        }
        unsigned int u = __float_as_uint(c);
        unsigned int mono = (u & 0x80000000u) ? ~u : (u | 0x80000000u);
        e[r] = ((unsigned long long)(~mono) << 32) | (unsigned int)s;
    }
    wave_sort512(e, lane);
    if (lane < 16) {
        #pragma unroll
        for (int r = 0; r < 8; ++r) cand[wv * 128 + lane * 8 + r] = e[r];
    }
    __syncthreads();
    if (wv == 0) {
        #pragma unroll
        for (int r = 0; r < 8; ++r) e[r] = cand[lane * 8 + r];
        wave_sort512(e, lane);
        if (lane < 16) {
            int* idx_out = (blk & 1) ? (val_idx + b * KC) : (key_idx + b * KC);
            float* oidx  = out_idx_base + ((blk & 1) ? B_ * KC : 0) + b * KC;
            #pragma unroll
            for (int r = 0; r < 8; ++r) {
                int sel = (int)(e[r] & 0xffffffffu);
                idx_out[lane * 8 + r] = sel;
                oidx[lane * 8 + r] = (float)sel;
            }
        }
    }
}

// ------------------------------------------------------------------
// L1: topk (blocks 3072..3079) + weight transpose/convert (0..3071).
// ------------------------------------------------------------------
__global__ __launch_bounds__(256) void prep_kernel(
    const float* __restrict__ Wk, const float* __restrict__ Wv,
    const float* __restrict__ Wbil, unsigned short* __restrict__ Wt,
    const float* __restrict__ logits, const int* __restrict__ mask,
    int* __restrict__ key_idx, int* __restrict__ val_idx,
    float* __restrict__ out_idx)
{
    __shared__ float tile[32][33];
    __shared__ unsigned long long cand[512];
    const int tid = threadIdx.x;
    if (blockIdx.x < 3072) {
        const int z = blockIdx.x >> 10;
        const int remb = blockIdx.x & 1023;
        const float* Win = (z == 0) ? Wk : (z == 1) ? Wv : Wbil;
        unsigned short* out = Wt + (size_t)z * H_ * H_;
        const int n0 = (remb & 31) * 32, k0 = (remb >> 5) * 32;
        const int r = tid >> 3, c0 = (tid & 7) * 4;
        float4 v = *(const float4*)(Win + (size_t)(k0 + r) * H_ + n0 + c0);
        tile[r][c0 + 0] = v.x; tile[r][c0 + 1] = v.y;
        tile[r][c0 + 2] = v.z; tile[r][c0 + 3] = v.w;
        __syncthreads();
        short4 o;
        o.x = (short)f2b(tile[c0 + 0][r]);
        o.y = (short)f2b(tile[c0 + 1][r]);
        o.z = (short)f2b(tile[c0 + 2][r]);
        o.w = (short)f2b(tile[c0 + 3][r]);
        *(short4*)(out + (size_t)(n0 + r) * H_ + k0 + c0) = o;
        return;
    }
    topk_block(logits, mask, blockIdx.x - 3072, key_idx, val_idx, out_idx,
               cand, tid);
}

// ------------------------------------------------------------------
// L2/L3: MFMA GEMM, 32x32 tile per wave. If idx != null, A rows are
// gathered from seq (f32) and converted to bf16 in-register; else A is
// a bf16 matrix. Wt is the N-major (transposed) bf16 weight.
// ------------------------------------------------------------------
__global__ __launch_bounds__(64) void gemm_mfma_kernel(
    const float* __restrict__ seq,          // [B,S,H] f32 (used when idx)
    const unsigned short* __restrict__ Abf, // [M,H] bf16 (used when !idx)
    const int* __restrict__ idx0,           // key_idx base or nullptr
    const unsigned short* __restrict__ Wt,  // [z][1024][1024] bf16 N-major
    const float* __restrict__ b0, const float* __restrict__ b1,
    unsigned short* __restrict__ Cout)      // [z*512+512][1024] bf16
{
    const int z = blockIdx.z;
    Wt   += (size_t)z * H_ * H_;
    Cout += (size_t)z * 512 * H_;
    const float* bias = z ? b1 : b0;
    const int* idx = idx0 ? (idx0 + z * 512) : nullptr;

    const int l  = threadIdx.x;
    const int m0 = blockIdx.y * 32;
    const int n0 = blockIdx.x * 32;
    const int r  = l & 15;
    const int kb = (l >> 4) * 8;

    f32x4 acc[2][2] = {};
    const float* s0 = nullptr; const float* s1 = nullptr;
    const unsigned short* a0 = nullptr; const unsigned short* a1 = nullptr;
    if (idx) {
        int gm0 = m0 + r, gm1 = m0 + 16 + r;
        s0 = seq + ((size_t)(gm0 >> 7) * S_ + idx[gm0]) * H_ + kb;
        s1 = seq + ((size_t)(gm1 >> 7) * S_ + idx[gm1]) * H_ + kb;
    } else {
        a0 = Abf + (size_t)(m0 + r) * H_ + kb;
        a1 = a0 + 16 * H_;
    }
    const unsigned short* w0 = Wt + (size_t)(n0 + r) * H_ + kb;
    const unsigned short* w1 = w0 + 16 * H_;

    #pragma unroll 4
    for (int k0 = 0; k0 < H_; k0 += 32) {
        bf16x8 av[2], bv[2];
        if (idx) {
            #pragma unroll
            for (int i = 0; i < 2; ++i) {
                const float* sp = i ? s1 : s0;
                float4 va = *(const float4*)(sp + k0);
                float4 vb = *(const float4*)(sp + k0 + 4);
                av[i][0] = (short)f2b(va.x); av[i][1] = (short)f2b(va.y);
                av[i][2] = (short)f2b(va.z); av[i][3] = (short)f2b(va.w);
                av[i][4] = (short)f2b(vb.x); av[i][5] = (short)f2b(vb.y);
                av[i][6] = (short)f2b(vb.z); av[i][7] = (short)f2b(vb.w);
            }
        } else {
            av[0] = *(const bf16x8*)(a0 + k0);
            av[1] = *(const bf16x8*)(a1 + k0);
        }
        bv[0] = *(const bf16x8*)(w0 + k0);
        bv[1] = *(const bf16x8*)(w1 + k0);
        #pragma unroll
        for (int i = 0; i < 2; ++i)
            #pragma unroll
            for (int j = 0; j < 2; ++j)
                acc[i][j] = __builtin_amdgcn_mfma_f32_16x16x32_bf16(
                    av[i], bv[j], acc[i][j], 0, 0, 0);
    }

    const int orow = (l >> 4) * 4, ocol = l & 15;
    #pragma unroll
    for (int i = 0; i < 2; ++i)
        #pragma unroll
        for (int j = 0; j < 2; ++j) {
            int n = n0 + j * 16 + ocol;
            float bv_ = bias ? bias[n] : 0.0f;
            #pragma unroll
            for (int g = 0; g < 4; ++g)
                Cout[(size_t)(m0 + i * 16 + orow + g) * H_ + n] =
                    f2b(acc[i][j][g] + bv_);
        }
}

// ------------------------------------------------------------------
// L4: biaffine (4-wave K-split MFMA) fused with spatial MLP.
// 256 blocks x 256 thr; block = (b, 16x16 biaffine tile); 1 elem/thread.
// ------------------------------------------------------------------
__global__ __launch_bounds__(256) void biasp_kernel(
    const unsigned short* __restrict__ kbt,
    const unsigned short* __restrict__ vrep,
    const float* __restrict__ bbil, const float* __restrict__ bboxes,
    const int* __restrict__ key_idx, const int* __restrict__ val_idx,
    const float* __restrict__ Ws1, const float* __restrict__ bs1,
    const float* __restrict__ Ws2, const float* __restrict__ bs2,
    const float* __restrict__ Wf1, const float* __restrict__ bf1,
    const float* __restrict__ Wf2, const float* __restrict__ bf2,
    float* __restrict__ out)
{
    __shared__ float part[4][16][16];
    __shared__ float4 sWs1T[128];
    __shared__ float  sbs1[64];
    __shared__ float4 sWs2v[512];
    __shared__ float4 sbs2v[8];
    __shared__ float  sWf1c0[16];
    __shared__ float4 sWf1v[128];
    __shared__ float  sbf1[16];
    __shared__ float  sWf2[16];

    const int tid = threadIdx.x;
    for (int i = tid; i < 128; i += 256) {
        int j = i >> 1, q = i & 1;
        sWs1T[i] = (float4){Ws1[(4*q+0)*64+j], Ws1[(4*q+1)*64+j],
                            Ws1[(4*q+2)*64+j], Ws1[(4*q+3)*64+j]};
    }
    for (int i = tid; i < 64;  i += 256) sbs1[i] = bs1[i];
    for (int i = tid; i < 512; i += 256) sWs2v[i] = ((const float4*)Ws2)[i];
    if (tid < 8)  sbs2v[tid] = ((const float4*)bs2)[tid];
    if (tid < 16) sWf1c0[tid] = Wf1[tid];
    for (int i = tid; i < 128; i += 256) {
        int t = i >> 3, q = i & 7;
        sWf1v[i] = (float4){Wf1[(1+4*q+0)*16+t], Wf1[(1+4*q+1)*16+t],
                            Wf1[(1+4*q+2)*16+t], Wf1[(1+4*q+3)*16+t]};
    }
    if (tid < 16) sbf1[tid] = bf1[tid];
    if (tid < 16) sWf2[tid] = Wf2[tid];

    const int b = blockIdx.x >> 6;
    const int t = blockIdx.x & 63;
    const int m0 = (t >> 3) * 16, n0 = (t & 7) * 16;
    const int lane = tid & 63, wv = tid >> 6;
    const int r = lane & 15, kq = (lane >> 4) * 8;

    f32x4 acc = {};
    const unsigned short* a0 = kbt  + (size_t)(b * KC + m0 + r) * H_ + kq;
    const unsigned short* w0 = vrep + (size_t)(b * KC + n0 + r) * H_ + kq;
    #pragma unroll
    for (int kk = 0; kk < 8; ++kk) {
        int k0 = wv * 256 + kk * 32;
        acc = __builtin_amdgcn_mfma_f32_16x16x32_bf16(
            *(const bf16x8*)(a0 + k0), *(const bf16x8*)(w0 + k0), acc, 0, 0, 0);
    }
    const int orow = (lane >> 4) * 4, ocol = lane & 15;
    #pragma unroll
    for (int g = 0; g < 4; ++g) part[wv][orow + g][ocol] = acc[g];
    __syncthreads();

    const int kl = tid >> 4, vl = tid & 15;
    float c0 = part[0][kl][vl] + part[1][kl][vl]
             + part[2][kl][vl] + part[3][kl][vl] + bbil[0];
    const int kg = m0 + kl, vg = n0 + vl;

    const float* kbx = bboxes + ((size_t)b * S_ + key_idx[b * KC + kg]) * 4;
    const float* vbx = bboxes + ((size_t)b * S_ + val_idx[b * KC + vg]) * 4;
    float k0_ = kbx[0], k1_ = kbx[1], k2_ = kbx[2], k3_ = kbx[3];
    float v0_ = vbx[0], v1_ = vbx[1], v2_ = vbx[2], v3_ = vbx[3];

    float kcx = (k0_ + k2_) * 0.5f, kcy = (k1_ + k3_) * 0.5f;
    float vcx = (v0_ + v2_) * 0.5f, vcy = (v1_ + v3_) * 0.5f;
    float dx = vcx - kcx, dy = vcy - kcy;
    float dist = sqrtf(dx * dx + dy * dy + EPSF);
    float angle = atan2f(dy, dx);
    float kh = k3_ - k1_, vh = v3_ - v1_, kw = k2_ - k0_, vw = v2_ - v0_;
    float h_ov = fmaxf(fminf(k3_, v3_) - fmaxf(k1_, v1_), 0.0f);
    float h_align = h_ov / (fminf(kh, vh) + EPSF);
    float v_ov = fmaxf(fminf(k2_, v2_) - fmaxf(k0_, v0_), 0.0f);
    float v_align = v_ov / (fminf(kw, vw) + EPSF);
    float area_ratio = (vh * vw) / (kh * kw + EPSF);
    float aspect = (vw / (vh + EPSF)) / (kw / (kh + EPSF));

    float4 sfa = {dx, dy, dist, angle};
    float4 sfb = {h_align, v_align, area_ratio, aspect};

    float4 h2v[8];
    #pragma unroll
    for (int q = 0; q < 8; ++q) h2v[q] = sbs2v[q];
    for (int j = 0; j < 64; ++j) {
        float4 w1a = sWs1T[j * 2], w1b = sWs1T[j * 2 + 1];
        float a = sbs1[j]
                + sfa.x * w1a.x + sfa.y * w1a.y + sfa.z * w1a.z + sfa.w * w1a.w
                + sfb.x * w1b.x + sfb.y * w1b.y + sfb.z * w1b.z + sfb.w * w1b.w;
        a = fmaxf(a, 0.0f);
        const float4* w2 = &sWs2v[j * 8];
        #pragma unroll
        for (int q = 0; q < 8; ++q) {
            float4 w = w2[q];
            h2v[q].x += a * w.x; h2v[q].y += a * w.y;
            h2v[q].z += a * w.z; h2v[q].w += a * w.w;
        }
    }
    float score = bf2[0];
    for (int tt = 0; tt < 16; ++tt) {
        float f = sbf1[tt] + c0 * sWf1c0[tt];
        const float4* w = &sWf1v[tt * 8];
        #pragma unroll
        for (int q = 0; q < 8; ++q) {
            float4 ww = w[q];
            f += h2v[q].x * ww.x + h2v[q].y * ww.y
               + h2v[q].z * ww.z + h2v[q].w * ww.w;
        }
        score += fmaxf(f, 0.0f) * sWf2[tt];
    }
    out[((size_t)b * KC + kg) * KC + vg] = score;
}

// ------------------------------------------------------------------
extern "C" void kernel_launch(void* const* d_in, const int* in_sizes, int n_in,
                              void* d_out, int out_size, void* d_ws, size_t ws_size,
                              hipStream_t stream) {
    const float* seq    = (const float*)d_in[0];
    const float* logits = (const float*)d_in[1];
    const float* bboxes = (const float*)d_in[2];
    const int*   mask   = (const int*)d_in[3];
    const float* Wk   = (const float*)d_in[4];
    const float* bk   = (const float*)d_in[5];
    const float* Wv   = (const float*)d_in[6];
    const float* bv   = (const float*)d_in[7];
    const float* Wbil = (const float*)d_in[8];
    const float* bbil = (const float*)d_in[9];
    const float* Ws1  = (const float*)d_in[10];
    const float* bs1  = (const float*)d_in[11];
    const float* Ws2  = (const float*)d_in[12];
    const float* bs2  = (const float*)d_in[13];
    const float* Wf1  = (const float*)d_in[14];
    const float* bf1  = (const float*)d_in[15];
    const float* Wf2  = (const float*)d_in[16];
    const float* bf2  = (const float*)d_in[17];

    float* out = (float*)d_out;
    char* ws = (char*)d_ws;

    // ws: idx @64 | Wt 6MB @8192 | reps 2MB (krep|vrep) | kbt 1MB
    int* key_idx = (int*)(ws + 64);
    int* val_idx = key_idx + B_ * KC;
    unsigned short* Wt   = (unsigned short*)(ws + 8192);
    unsigned short* reps = Wt + (size_t)3 * H_ * H_;
    unsigned short* kbt  = reps + (size_t)1024 * H_;

    // L1: topk + weight transposes
    prep_kernel<<<3080, 256, 0, stream>>>(Wk, Wv, Wbil, Wt,
                                          logits, mask, key_idx, val_idx,
                                          out + B_ * KC * KC);
    // L2: krep (z=0) + vrep (z=1), inline gather from seq
    gemm_mfma_kernel<<<dim3(32, 16, 2), 64, 0, stream>>>(
        seq, nullptr, key_idx, Wt, bk, bv, reps);
    // L3: kbt = krep @ WbilT (no gather, no bias)
    gemm_mfma_kernel<<<dim3(32, 16, 1), 64, 0, stream>>>(
        nullptr, reps, nullptr, Wt + (size_t)2 * H_ * H_,
        nullptr, nullptr, kbt);
    // L4: biaffine + spatial MLP
    biasp_kernel<<<256, 256, 0, stream>>>(kbt, reps + (size_t)512 * H_,
                                          bbil, bboxes, key_idx, val_idx,
                                          Ws1, bs1, Ws2, bs2,
                                          Wf1, bf1, Wf2, bf2, out);
}